// Round 5
// baseline (221.502 us; speedup 1.0000x reference)
//
#include <hip/hip_runtime.h>

// FWHT over last dim (n = 4096), normalized by 1/64.
// R5: 4 ROWS PER BLOCK, software-pipelined with double-buffered LDS.
//   Theory: R3 (LDS-op cut) and R4 (store flavor) were both null -> kernel's
//   compute/LDS path is fully hidden; remaining gap (if any) vs the ~43 us
//   memory floor is READ-STREAM DISCONTINUITY: 1-row blocks load 4 KiB/thread
//   then go memory-silent through P1 + 2 barriers + LDS phases. Fix: issue row
//   r+1's nontemporal loads BEFORE computing row r (T14 issue-early), so reads
//   stay in flight across every barrier. Double-buffer LDS (2 x 16 KiB) keeps
//   2 barriers/row; rotation is race-free: row r's P3 gather of buf[r&1]
//   precedes row r+1's two barriers, which precede row r+2's write to buf[r&1].
// Per-row phase structure (verified R1/R3, SQ_LDS_BANK_CONFLICT == 0):
//   P1 (regs): bits {0,1} (float4 comps), {10,11} (across j),
//              {6,7} (v_permlane16/32_swap builtins; el bit6=lane bit4, bit7=lane5)
//   P2 (LDS):  bits {2..5} scalar b32, conflict-free XOR swizzle
//   P3 (LDS):  bits {8,9} b128 gather + reg butterfly + scale + coalesced nt-store
// LDS swizzle on float4 idx: F ^= (F>>4)&7 (involutive bijection).
//   P1 write at t ^ ((t>>4)&7) + 256j: conflict-free b128.
//   P2 bank = (t&3) + 4*((r&7)^((t>>2)&7)): 32 banks/half-wave, 2-way = free.
//   P3 read at F ^ ((F>>4)&7), F = l+64m+256w: conflict-free b128.
// permlane pair-butterfly: swap(x,y) -> s,d -> swap(s,d) = bfly(x),bfly(y) in
// original positions (2 swaps + 2 add/sub per reg pair, VALU pipe only).
// __launch_bounds__(256,4): 4 blocks/CU min (16 waves/CU), VGPR cap 128 — enough
// MLP (16 waves x 4 KiB loads in flight >> 9 KB BW-latency product).

using v4 = __attribute__((ext_vector_type(4))) float;
using u2 = __attribute__((ext_vector_type(2))) unsigned;

__device__ __forceinline__ void bfly_perm32(float& x, float& y) {
    u2 r = __builtin_amdgcn_permlane32_swap(__float_as_uint(x), __float_as_uint(y),
                                            false, false);
    float u = __uint_as_float(r[0]), v = __uint_as_float(r[1]);
    float s = u + v, d = u - v;
    u2 r2 = __builtin_amdgcn_permlane32_swap(__float_as_uint(s), __float_as_uint(d),
                                             false, false);
    x = __uint_as_float(r2[0]); y = __uint_as_float(r2[1]);
}

__device__ __forceinline__ void bfly_perm16(float& x, float& y) {
    u2 r = __builtin_amdgcn_permlane16_swap(__float_as_uint(x), __float_as_uint(y),
                                            false, false);
    float u = __uint_as_float(r[0]), v = __uint_as_float(r[1]);
    float s = u + v, d = u - v;
    u2 r2 = __builtin_amdgcn_permlane16_swap(__float_as_uint(s), __float_as_uint(d),
                                             false, false);
    x = __uint_as_float(r2[0]); y = __uint_as_float(r2[1]);
}

__device__ __forceinline__ void had16(float x[16]) {
#pragma unroll
    for (int h = 1; h < 16; h <<= 1) {
#pragma unroll
        for (int i = 0; i < 16; ++i) {
            if (!(i & h)) {
                float a = x[i], b = x[i ^ h];
                x[i] = a + b; x[i ^ h] = a - b;
            }
        }
    }
}

__global__ void __launch_bounds__(256, 4) fwht4096_kernel(const float* __restrict__ in,
                                                          float* __restrict__ out,
                                                          int rows) {
    __shared__ float lds[2][4096];
    const int t = threadIdx.x;
    const int row0 = blockIdx.x * 4;
    const v4* in4 = reinterpret_cast<const v4*>(in) + (size_t)row0 * 1024;
    v4* out4 = reinterpret_cast<v4*>(out) + (size_t)row0 * 1024;

    v4 cur[4], nxt[4];
#pragma unroll
    for (int j = 0; j < 4; ++j) cur[j] = __builtin_nontemporal_load(&in4[t + 256 * j]);

#pragma unroll
    for (int r = 0; r < 4; ++r) {
        if (row0 + r >= rows) break;  // block-uniform guard (rows % 4 tail)

        // ---- issue next row's loads EARLY (in flight across barriers below) ----
        if (r < 3 && row0 + r + 1 < rows) {
#pragma unroll
            for (int j = 0; j < 4; ++j)
                nxt[j] = __builtin_nontemporal_load(&in4[(r + 1) * 1024 + t + 256 * j]);
        }

        // ---------------- P1: bits {0,1,10,11} + {6,7} via permlane ----------------
#pragma unroll
        for (int j = 0; j < 4; ++j) {  // bits 0,1 (within float4)
            float a = cur[j][0], b = cur[j][1], c = cur[j][2], d = cur[j][3];
            float ab = a + b, amb = a - b, cd = c + d, cmd = c - d;
            cur[j][0] = ab + cd; cur[j][1] = amb + cmd;
            cur[j][2] = ab - cd; cur[j][3] = amb - cmd;
        }
        {  // bits 10,11 (across j)
            v4 s0 = cur[0] + cur[1], d0 = cur[0] - cur[1];
            v4 s1 = cur[2] + cur[3], d1 = cur[2] - cur[3];
            cur[0] = s0 + s1; cur[2] = s0 - s1;
            cur[1] = d0 + d1; cur[3] = d0 - d1;
        }
#pragma unroll
        for (int e = 0; e < 4; ++e) {  // bits 6,7 (lane bits 4,5)
            float a0 = cur[0][e], a1 = cur[1][e], a2 = cur[2][e], a3 = cur[3][e];
            bfly_perm16(a0, a1); bfly_perm16(a2, a3);
            bfly_perm32(a0, a1); bfly_perm32(a2, a3);
            cur[0][e] = a0; cur[1][e] = a1; cur[2][e] = a2; cur[3][e] = a3;
        }
        {  // LDS write at swizzled float4 idx
            v4* l4 = reinterpret_cast<v4*>(lds[r & 1]);
            const int wb = t ^ ((t >> 4) & 7);
#pragma unroll
            for (int j = 0; j < 4; ++j) l4[wb + 256 * j] = cur[j];
        }
        __syncthreads();

        // ---------------- P2: bits {2..5} ----------------
        {
            float x[16];
            float* l = lds[r & 1];
            const int b2 = (t & 3) + 64 * (t >> 2);
            const int s2 = (t >> 2) & 7;
#pragma unroll
            for (int q = 0; q < 16; ++q) x[q] = l[b2 + 4 * (q ^ s2)];
            had16(x);
#pragma unroll
            for (int q = 0; q < 16; ++q) l[b2 + 4 * (q ^ s2)] = x[q];
        }
        __syncthreads();

        // ---------------- P3: bits {8,9} + gather + nt-store ----------------
        {
            const v4* l4 = reinterpret_cast<const v4*>(lds[r & 1]);
            const int l = t & 63, w = t >> 6;
            v4 g[4];
#pragma unroll
            for (int m = 0; m < 4; ++m) {
                const int F = l + 64 * m + 256 * w;
                const int rb = F ^ ((F >> 4) & 7);
                g[m] = l4[rb];
            }
            v4 s0 = g[0] + g[1], d0 = g[0] - g[1];
            v4 s1 = g[2] + g[3], d1 = g[2] - g[3];
            const float scale = 0.015625f;  // 1/64 = 1/sqrt(4096), exact
            v4* o = out4 + r * 1024;
            __builtin_nontemporal_store((s0 + s1) * scale, &o[l + 256 * w]);
            __builtin_nontemporal_store((d0 + d1) * scale, &o[l + 64 + 256 * w]);
            __builtin_nontemporal_store((s0 - s1) * scale, &o[l + 128 + 256 * w]);
            __builtin_nontemporal_store((d0 - d1) * scale, &o[l + 192 + 256 * w]);
        }

#pragma unroll
        for (int j = 0; j < 4; ++j) cur[j] = nxt[j];
    }
}

extern "C" void kernel_launch(void* const* d_in, const int* in_sizes, int n_in,
                              void* d_out, int out_size, void* d_ws, size_t ws_size,
                              hipStream_t stream) {
    const float* x = (const float*)d_in[0];
    float* out = (float*)d_out;
    const int rows = in_sizes[0] >> 12;  // / 4096
    const int nb = (rows + 3) >> 2;      // 4 rows per block
    fwht4096_kernel<<<dim3(nb), dim3(256), 0, stream>>>(x, out, rows);
}

// Round 7
// 219.705 us; speedup vs baseline: 1.0082x; 1.0082x over previous
//
#include <hip/hip_runtime.h>

// FWHT over last dim (n = 4096), normalized by 1/64. One block (256 thr) per row.
// FINAL (R3/R4-verified, ~218 us): 12 butterfly bits, 3 phases, TWO LDS
// round-trips. Session evidence that this is the composite floor:
//   - headline = 2x512MiB poison fills (~160us, 84% HBM peak, harness-owned)
//     + out memset (~20us) + kernel (~38-40us vs 268MB copy floor of 40-43us).
//   - R3: LDS ops 72->40 + one fewer barrier = +0.0us (LDS pipe fully hidden)
//   - R4: cached vs nontemporal stores = +0.0us (write path off critical path)
//   - R5: 4-row issue-early pipeline = +3us (no read-gap slack to recover)
//   - R6: nt-store variant flaked a post-timing recheck once (first check +
//     tripwire passed; same source passed R3) -> keep the equally-fast CACHED
//     store path; nt retained on loads only (read-once input, don't pollute L3).
// Phase structure:
//   P1 (regs): bits {0,1}  (float4 components)
//              bits {10,11} (across j = 4 loaded float4s)
//              bits {6,7}   (v_permlane16/32_swap BUILTINS — element bit6 =
//                            lane bit4, bit7 = lane bit5; VALU pipe, no LDS.
//                            Raw inline-asm version FAILS: VALU->permlane
//                            wait-state hazard invisible inside asm strings.)
//   P2 (LDS):  bits {2..5}  (scalar b32 exchange, conflict-free swizzle)
//   P3 (LDS):  bits {8,9}   (b128 gather, reg butterfly, scale, coalesced store)
// All LDS addresses use the involutive XOR swizzle on float4 idx: F ^= (F>>4)&7.
// Bank math (SQ_LDS_BANK_CONFLICT == 0 measured):
//   P1 write at wb = t ^ ((t>>4)&7) + 256j: per-16-lane group XOR term constant
//     -> residues mod 8 each hit exactly twice -> conflict-free b128.
//   P2 r/w: bank = (t&3) + 4*((r&7)^((t>>2)&7)) -> 32 distinct banks per
//     half-wave, 2-way across halves -> free (m136).
//   P3 read at F = l+64m+256w, rb = F ^ ((F>>4)&7): (F>>4)&7 constant per
//     16-lane group -> conflict-free b128.
// permlane pair-butterfly (vdst odd 16/32-lane rows <-> src even rows):
//   swap(x,y) -> s,d = sum/diff -> swap(s,d) lands bfly(x) in reg0, bfly(y) in
//   reg1, outputs in original positions. 2 swaps + 2 add/sub per reg pair.

using v4 = __attribute__((ext_vector_type(4))) float;
using u2 = __attribute__((ext_vector_type(2))) unsigned;

__device__ __forceinline__ void bfly_perm32(float& x, float& y) {
    u2 r = __builtin_amdgcn_permlane32_swap(__float_as_uint(x), __float_as_uint(y),
                                            false, false);
    float u = __uint_as_float(r[0]), v = __uint_as_float(r[1]);
    float s = u + v, d = u - v;
    u2 r2 = __builtin_amdgcn_permlane32_swap(__float_as_uint(s), __float_as_uint(d),
                                             false, false);
    x = __uint_as_float(r2[0]); y = __uint_as_float(r2[1]);
}

__device__ __forceinline__ void bfly_perm16(float& x, float& y) {
    u2 r = __builtin_amdgcn_permlane16_swap(__float_as_uint(x), __float_as_uint(y),
                                            false, false);
    float u = __uint_as_float(r[0]), v = __uint_as_float(r[1]);
    float s = u + v, d = u - v;
    u2 r2 = __builtin_amdgcn_permlane16_swap(__float_as_uint(s), __float_as_uint(d),
                                             false, false);
    x = __uint_as_float(r2[0]); y = __uint_as_float(r2[1]);
}

__device__ __forceinline__ void had16(float x[16]) {
#pragma unroll
    for (int h = 1; h < 16; h <<= 1) {
#pragma unroll
        for (int i = 0; i < 16; ++i) {
            if (!(i & h)) {
                float a = x[i], b = x[i ^ h];
                x[i] = a + b; x[i ^ h] = a - b;
            }
        }
    }
}

__global__ void __launch_bounds__(256) fwht4096_kernel(const float* __restrict__ in,
                                                       float* __restrict__ out) {
    __shared__ float lds[4096];
    const int t = threadIdx.x;
    const size_t base = (size_t)blockIdx.x * 4096;
    const v4* in4 = reinterpret_cast<const v4*>(in + base);
    v4* out4 = reinterpret_cast<v4*>(out + base);

    // ---------------- P1: bits {0,1,10,11} in regs + {6,7} via permlane ----------------
    v4 v[4];
#pragma unroll
    for (int j = 0; j < 4; ++j) v[j] = __builtin_nontemporal_load(&in4[t + 256 * j]);

#pragma unroll
    for (int j = 0; j < 4; ++j) {  // bits 0,1 (within float4)
        float a = v[j][0], b = v[j][1], c = v[j][2], d = v[j][3];
        float ab = a + b, amb = a - b, cd = c + d, cmd = c - d;
        v[j][0] = ab + cd; v[j][1] = amb + cmd; v[j][2] = ab - cd; v[j][3] = amb - cmd;
    }
    {  // bits 10,11 (across j)
        v4 s0 = v[0] + v[1], d0 = v[0] - v[1];
        v4 s1 = v[2] + v[3], d1 = v[2] - v[3];
        v[0] = s0 + s1; v[2] = s0 - s1;
        v[1] = d0 + d1; v[3] = d0 - d1;
    }
    {  // bits 6,7 via permlane swaps (element bit6 = lane bit4, bit7 = lane bit5)
#pragma unroll
        for (int e = 0; e < 4; ++e) {
            float a0 = v[0][e], a1 = v[1][e], a2 = v[2][e], a3 = v[3][e];
            bfly_perm16(a0, a1); bfly_perm16(a2, a3);
            bfly_perm32(a0, a1); bfly_perm32(a2, a3);
            v[0][e] = a0; v[1][e] = a1; v[2][e] = a2; v[3][e] = a3;
        }
    }
    {  // LDS write at swizzled float4 idx (t ^ ((t>>4)&7)) + 256j
        v4* l4 = reinterpret_cast<v4*>(lds);
        const int wb = t ^ ((t >> 4) & 7);
#pragma unroll
        for (int j = 0; j < 4; ++j) l4[wb + 256 * j] = v[j];
    }
    __syncthreads();

    // ---------------- P2: bits {2..5} ----------------
    // logical elem = (t&3) + 4r + 64*(t>>2); physical = logical with r ^= s2
    {
        float x[16];
        const int b2 = (t & 3) + 64 * (t >> 2);
        const int s2 = (t >> 2) & 7;
#pragma unroll
        for (int r = 0; r < 16; ++r) x[r] = lds[b2 + 4 * (r ^ s2)];
        had16(x);
#pragma unroll
        for (int r = 0; r < 16; ++r) lds[b2 + 4 * (r ^ s2)] = x[r];
    }
    __syncthreads();

    // ---------------- P3: bits {8,9} + gather + vectorized cached store ----------------
    // thread (w,l) reads float4s at logical f4idx F = l + 64m + 256w (m = 0..3);
    // element bits {9:8} = m -> butterfly across m; store to out4[l + 64m + 256w]
    // (per m, 64 lanes cover a contiguous 1KB segment -> fully coalesced,
    //  whole-line writes -> L2 write-allocate without RFO).
    {
        const v4* l4 = reinterpret_cast<const v4*>(lds);
        const int l = t & 63, w = t >> 6;
        v4 g[4];
#pragma unroll
        for (int m = 0; m < 4; ++m) {
            const int F = l + 64 * m + 256 * w;
            const int rb = F ^ ((F >> 4) & 7);
            g[m] = l4[rb];
        }
        v4 s0 = g[0] + g[1], d0 = g[0] - g[1];
        v4 s1 = g[2] + g[3], d1 = g[2] - g[3];
        const float scale = 0.015625f;  // 1/64 = 1/sqrt(4096), exact
        out4[l + 256 * w]       = (s0 + s1) * scale;
        out4[l + 64 + 256 * w]  = (d0 + d1) * scale;
        out4[l + 128 + 256 * w] = (s0 - s1) * scale;
        out4[l + 192 + 256 * w] = (d0 - d1) * scale;
    }
}

extern "C" void kernel_launch(void* const* d_in, const int* in_sizes, int n_in,
                              void* d_out, int out_size, void* d_ws, size_t ws_size,
                              hipStream_t stream) {
    const float* x = (const float*)d_in[0];
    float* out = (float*)d_out;
    const int rows = in_sizes[0] >> 12;  // / 4096
    fwht4096_kernel<<<dim3(rows), dim3(256), 0, stream>>>(x, out);
}